// Round 1
// baseline (1352.302 us; speedup 1.0000x reference)
//
#include <hip/hip_runtime.h>
#include <stdint.h>

#define S_LEN 2048
#define D_HEAD 64
#define NBH 64            // B*H = 4*16
#define QBLK 32
#define KBLK 64
#define NITER (S_LEN / KBLK)   // 32

typedef __attribute__((ext_vector_type(8))) short short8;  // 8 x bf16
typedef __attribute__((ext_vector_type(4))) float f32x4;

// LDS layout (bytes)
#define K_OFF   0        // 64 rows x 128B (bf16 K tile)      = 8192
#define VT_OFF  8192     // 64 rows x 128B (bf16 V^T tile)    = 8192 (shared w/ Q staging)
#define Q_OFF   8192
#define P_OFF   16384    // 32 rows x 128B (bf16 P tile)      = 4096
#define MB_OFF  20480    // 4 waves x 32 iters x 2 ct x 4 reg x 8B = 8192 (mask ballots)
#define LP_OFF  28672    // 2 x 32 floats (row-sum partials)  = 256
#define SMEM_BYTES 28928

// XOR swizzle within a 128B row: spreads 16B chunks across banks.
__device__ __forceinline__ int swz1(int row, int b) {
  return row * 128 + (b ^ ((row & 7) << 4));
}
// variant for P tile (rows accessed 4 apart on writes)
__device__ __forceinline__ int swz2(int row, int b) {
  return row * 128 + (b ^ (((row >> 1) & 7) << 4));
}

__device__ __forceinline__ short f2b(float x) {  // fp32 -> bf16 RNE
  unsigned u = __float_as_uint(x);
  unsigned r = 0x7FFFu + ((u >> 16) & 1u);
  return (short)((u + r) >> 16);
}

// Detect mask element width: int32/float32 words are in {0,1,0x3F800000};
// byte-packed bools produce other word values w.h.p. over 4096 samples.
__global__ void detect_mask_kernel(const unsigned* m, int* flag) {
  unsigned v = m[blockIdx.x * 256 + threadIdx.x];
  if (v != 0u && v != 1u && v != 0x3F800000u) atomicOr(flag, 1);
}

template <bool BYTEMASK>
__device__ __forceinline__ void attn_body(
    char* smem, const float* Qg, const float* Kg, const float* Vg,
    const void* maskg, float* ctxg, float* attng) {

  const int tid = threadIdx.x;
  const int w = tid >> 6, l = tid & 63;
  const int lg = l >> 4, li = l & 15;
  const int rh = w >> 1, ch = w & 1;   // wave -> (row-half, col-half)
  const int qb = blockIdx.x, bh = blockIdx.y;
  const int qbase = qb * QBLK;

  const float* Qp = Qg + ((size_t)bh * S_LEN + qbase) * D_HEAD;
  const float* Kp = Kg + (size_t)bh * S_LEN * D_HEAD;
  const float* Vp = Vg + (size_t)bh * S_LEN * D_HEAD;
  float* attnp = attng + ((size_t)bh * S_LEN + qbase) * S_LEN;
  float* ctxp  = ctxg  + ((size_t)bh * S_LEN + qbase) * D_HEAD;
  const size_t mrow0 = ((size_t)bh * S_LEN + qbase) * S_LEN;

  // ---- stage Q (32x64 fp32 -> bf16 LDS, swizzled) ----
  {
    int row = tid >> 3, seg = tid & 7;
    const float* src = Qp + row * D_HEAD + seg * 8;
    float4 a = ((const float4*)src)[0];
    float4 b = ((const float4*)src)[1];
    short8 v;
    v[0] = f2b(a.x); v[1] = f2b(a.y); v[2] = f2b(a.z); v[3] = f2b(a.w);
    v[4] = f2b(b.x); v[5] = f2b(b.y); v[6] = f2b(b.z); v[7] = f2b(b.w);
    *(short8*)(smem + Q_OFF + swz1(row, seg * 16)) = v;
  }
  __syncthreads();
  // A-fragments of Q for this wave's 16 rows, kept in registers all kernel.
  short8 qfrag[2];
  {
    int row = rh * 16 + li;
    qfrag[0] = *(const short8*)(smem + Q_OFF + swz1(row, lg * 16));
    qfrag[1] = *(const short8*)(smem + Q_OFF + swz1(row, 64 + lg * 16));
  }
  __syncthreads();

  auto stageK = [&](int kbase) {
    int key = tid >> 2, seg = tid & 3;
    const float* src = Kp + ((size_t)(kbase + key)) * D_HEAD + seg * 16;
    float4 f0 = ((const float4*)src)[0];
    float4 f1 = ((const float4*)src)[1];
    float4 f2 = ((const float4*)src)[2];
    float4 f3 = ((const float4*)src)[3];
    short8 v0, v1;
    v0[0] = f2b(f0.x); v0[1] = f2b(f0.y); v0[2] = f2b(f0.z); v0[3] = f2b(f0.w);
    v0[4] = f2b(f1.x); v0[5] = f2b(f1.y); v0[6] = f2b(f1.z); v0[7] = f2b(f1.w);
    v1[0] = f2b(f2.x); v1[1] = f2b(f2.y); v1[2] = f2b(f2.z); v1[3] = f2b(f2.w);
    v1[4] = f2b(f3.x); v1[5] = f2b(f3.y); v1[6] = f2b(f3.z); v1[7] = f2b(f3.w);
    *(short8*)(smem + K_OFF + swz1(key, seg * 32)) = v0;
    *(short8*)(smem + K_OFF + swz1(key, seg * 32 + 16)) = v1;
  };

  // QK^T for this wave's 16x32 subtile (2 col-tiles x K=64 via 2 MFMAs each)
  auto qkt = [&](f32x4* accs) {
    #pragma unroll
    for (int ct = 0; ct < 2; ++ct) {
      int key = ch * 32 + ct * 16 + li;
      short8 b0 = *(const short8*)(smem + K_OFF + swz1(key, lg * 16));
      short8 b1 = *(const short8*)(smem + K_OFF + swz1(key, 64 + lg * 16));
      accs[ct] = __builtin_amdgcn_mfma_f32_16x16x32_bf16(qfrag[0], b0, accs[ct], 0, 0, 0);
      accs[ct] = __builtin_amdgcn_mfma_f32_16x16x32_bf16(qfrag[1], b1, accs[ct], 0, 0, 0);
    }
  };

  // ================= pass 1: row sums of exp(s) (masked), mask->ballot bits =================
  float l_acc[4] = {0.f, 0.f, 0.f, 0.f};
  for (int it = 0; it < NITER; ++it) {
    int kbase = it * KBLK;
    stageK(kbase);
    __syncthreads();
    f32x4 accs[2] = {{0.f,0.f,0.f,0.f},{0.f,0.f,0.f,0.f}};
    qkt(accs);
    #pragma unroll
    for (int reg = 0; reg < 4; ++reg) {
      int row = rh * 16 + lg * 4 + reg;
      float contrib = 0.f;
      #pragma unroll
      for (int ct = 0; ct < 2; ++ct) {
        int col = kbase + ch * 32 + ct * 16 + li;
        bool pred;
        if (BYTEMASK)
          pred = ((const unsigned char*)maskg)[mrow0 + (size_t)row * S_LEN + col] != 0;
        else
          pred = ((const unsigned*)maskg)[mrow0 + (size_t)row * S_LEN + col] != 0u;
        unsigned long long bal = __ballot(pred ? 1 : 0);
        if (l == 0)
          *(unsigned long long*)(smem + MB_OFF +
              (((w * NITER + it) * 2 + ct) * 4 + reg) * 8) = bal;
        float p = pred ? 0.f : __expf(accs[ct][reg] * 0.125f);
        contrib += p;
      }
      contrib += __shfl_xor(contrib, 1);
      contrib += __shfl_xor(contrib, 2);
      contrib += __shfl_xor(contrib, 4);
      contrib += __shfl_xor(contrib, 8);
      l_acc[reg] += contrib;
    }
    __syncthreads();
  }

  // combine the two col-halves' partial sums -> 1/l per row
  if (li == 0) {
    #pragma unroll
    for (int reg = 0; reg < 4; ++reg)
      *(float*)(smem + LP_OFF + ch * 128 + (rh * 16 + lg * 4 + reg) * 4) = l_acc[reg];
  }
  __syncthreads();
  float linv[4];
  #pragma unroll
  for (int reg = 0; reg < 4; ++reg) {
    int row = rh * 16 + lg * 4 + reg;
    float tot = *(const float*)(smem + LP_OFF + row * 4) +
                *(const float*)(smem + LP_OFF + 128 + row * 4);
    linv[reg] = 1.0f / tot;
  }

  // ================= pass 2: recompute scores, write attn, accumulate PV =================
  f32x4 acco[2] = {{0.f,0.f,0.f,0.f},{0.f,0.f,0.f,0.f}};
  for (int it = 0; it < NITER; ++it) {
    int kbase = it * KBLK;
    __syncthreads();          // protect K/Vt/P from prior-iter readers
    stageK(kbase);
    {   // stage V transposed: Vt[d][key] bf16, swizzled
      int key = l;
      int db = w;
      const float* src = Vp + ((size_t)(kbase + key)) * D_HEAD + db * 16;
      #pragma unroll
      for (int j = 0; j < 4; ++j) {
        float4 f = ((const float4*)src)[j];
        int d0 = db * 16 + j * 4;
        *(short*)(smem + VT_OFF + swz1(d0 + 0, key * 2)) = f2b(f.x);
        *(short*)(smem + VT_OFF + swz1(d0 + 1, key * 2)) = f2b(f.y);
        *(short*)(smem + VT_OFF + swz1(d0 + 2, key * 2)) = f2b(f.z);
        *(short*)(smem + VT_OFF + swz1(d0 + 3, key * 2)) = f2b(f.w);
      }
    }
    __syncthreads();
    f32x4 accs[2] = {{0.f,0.f,0.f,0.f},{0.f,0.f,0.f,0.f}};
    qkt(accs);
    #pragma unroll
    for (int reg = 0; reg < 4; ++reg) {
      int row = rh * 16 + lg * 4 + reg;
      #pragma unroll
      for (int ct = 0; ct < 2; ++ct) {
        int col = ch * 32 + ct * 16 + li;
        unsigned long long bal = *(const unsigned long long*)(smem + MB_OFF +
            (((w * NITER + it) * 2 + ct) * 4 + reg) * 8);
        bool pred = (bal >> l) & 1ull;
        float p = pred ? 0.f : __expf(accs[ct][reg] * 0.125f) * linv[reg];
        attnp[(size_t)row * S_LEN + kbase + col] = p;
        *(short*)(smem + P_OFF + swz2(row, col * 2)) = f2b(p);
      }
    }
    __syncthreads();
    // PV: O(16x32 per wave) += P(16x64) * V(64x, this tile)
    #pragma unroll
    for (int ks = 0; ks < 2; ++ks) {
      int prow = rh * 16 + li;
      short8 af = *(const short8*)(smem + P_OFF + swz2(prow, ks * 64 + lg * 16));
      #pragma unroll
      for (int ct2 = 0; ct2 < 2; ++ct2) {
        int d = ch * 32 + ct2 * 16 + li;
        short8 bf = *(const short8*)(smem + VT_OFF + swz1(d, ks * 64 + lg * 16));
        acco[ct2] = __builtin_amdgcn_mfma_f32_16x16x32_bf16(af, bf, acco[ct2], 0, 0, 0);
      }
    }
  }

  // epilogue: write context
  #pragma unroll
  for (int ct2 = 0; ct2 < 2; ++ct2) {
    #pragma unroll
    for (int reg = 0; reg < 4; ++reg) {
      int row = rh * 16 + lg * 4 + reg;
      int d = ch * 32 + ct2 * 16 + li;
      ctxp[(size_t)row * D_HEAD + d] = acco[ct2][reg];
    }
  }
}

__global__ void __launch_bounds__(256)
attn_kernel(const float* Q, const float* K, const float* V, const void* M,
            float* ctx, float* attn, const int* flag) {
  extern __shared__ char smem[];
  if (*flag)
    attn_body<true>(smem, Q, K, V, M, ctx, attn);
  else
    attn_body<false>(smem, Q, K, V, M, ctx, attn);
}

extern "C" void kernel_launch(void* const* d_in, const int* in_sizes, int n_in,
                              void* d_out, int out_size, void* d_ws, size_t ws_size,
                              hipStream_t stream) {
  const float* Q = (const float*)d_in[0];
  const float* K = (const float*)d_in[1];
  const float* V = (const float*)d_in[2];
  const void*  M = d_in[3];
  float* ctx  = (float*)d_out;
  float* attn = ctx + (size_t)NBH * S_LEN * D_HEAD;   // context first, then attn
  int* flag = (int*)d_ws;

  hipMemsetAsync(flag, 0, sizeof(int), stream);
  detect_mask_kernel<<<dim3(16), dim3(256), 0, stream>>>((const unsigned*)M, flag);

  dim3 grid(S_LEN / QBLK, NBH);
  attn_kernel<<<grid, dim3(256), SMEM_BYTES, stream>>>(Q, K, V, M, ctx, attn, flag);
}

// Round 2
// 644.976 us; speedup vs baseline: 2.0967x; 2.0967x over previous
//
#include <hip/hip_runtime.h>
#include <stdint.h>

#define S_LEN 2048
#define D_HEAD 64
#define NBH 64            // B*H = 4*16
#define QBLK 32
#define KBLK 64
#define NITER (S_LEN / KBLK)   // 32

typedef __attribute__((ext_vector_type(8))) short short8;  // 8 x bf16
typedef __attribute__((ext_vector_type(4))) float f32x4;

// LDS layout (bytes)
#define KB_OFF 0        // 2 x 8KB K tile double buffer
#define VT_OFF 16384    // 8KB V^T tile
#define P_OFF  24576    // 4KB P tile (also Q staging at start)
#define MB_OFF 28672    // 8KB mask bytes: [it][tid]
#define LP_OFF 36864    // 256B row-sum partials
#define SMEM_BYTES 37120

// XOR swizzle within a 128B row (16B chunk granularity)
__device__ __forceinline__ int swz1(int row, int b) {
  return row * 128 + (b ^ ((row & 7) << 4));
}
__device__ __forceinline__ int swz2(int row, int b) {
  return row * 128 + (b ^ (((row >> 1) & 7) << 4));
}

__device__ __forceinline__ short f2b(float x) {  // fp32 -> bf16 RNE
  unsigned u = __float_as_uint(x);
  unsigned r = 0x7FFFu + ((u >> 16) & 1u);
  return (short)((u + r) >> 16);
}
__device__ __forceinline__ float b2f(short s) {
  return __uint_as_float(((unsigned)(unsigned short)s) << 16);
}

__device__ __forceinline__ void gload_lds16(const void* g, void* l) {
  __builtin_amdgcn_global_load_lds(
      (const __attribute__((address_space(1))) unsigned int*)g,
      (__attribute__((address_space(3))) unsigned int*)l, 16, 0, 0);
}

// Detect mask element width: int32/float32 words are in {0,1,0x3F800000};
// byte-packed bools produce other word values w.h.p. over 4096 samples.
__global__ void detect_mask_kernel(const unsigned* m, int* flag) {
  unsigned v = m[blockIdx.x * 256 + threadIdx.x];
  if (v != 0u && v != 1u && v != 0x3F800000u) atomicOr(flag, 1);
}

// fp32 -> bf16, linear (for K)
__global__ void __launch_bounds__(256) convK_kernel(
    const float* __restrict__ in, short* __restrict__ out) {
  size_t i = ((size_t)blockIdx.x * 256 + threadIdx.x) * 8;
  float4 a = ((const float4*)(in + i))[0];
  float4 b = ((const float4*)(in + i))[1];
  short8 v;
  v[0] = f2b(a.x); v[1] = f2b(a.y); v[2] = f2b(a.z); v[3] = f2b(a.w);
  v[4] = f2b(b.x); v[5] = f2b(b.y); v[6] = f2b(b.z); v[7] = f2b(b.w);
  *(short8*)(out + i) = v;
}

// fp32 V[bh][s][d] -> bf16 Vt[bh][d][s] (64x64 tiles via LDS)
__global__ void __launch_bounds__(256) convVT_kernel(
    const float* __restrict__ V, short* __restrict__ out) {
  __shared__ __align__(16) short t[64 * 72];
  int tid = threadIdx.x;
  int kb = blockIdx.x * 64, bh = blockIdx.y;
  const float* src = V + ((size_t)bh * S_LEN + kb) * D_HEAD;
#pragma unroll
  for (int j = 0; j < 4; ++j) {
    int key = j * 16 + (tid >> 4), d0 = (tid & 15) * 4;
    float4 f = *(const float4*)(src + (size_t)key * D_HEAD + d0);
    t[(d0 + 0) * 72 + key] = f2b(f.x);
    t[(d0 + 1) * 72 + key] = f2b(f.y);
    t[(d0 + 2) * 72 + key] = f2b(f.z);
    t[(d0 + 3) * 72 + key] = f2b(f.w);
  }
  __syncthreads();
  int row = tid >> 2, seg = tid & 3;
  short8 v0 = *(const short8*)(t + row * 72 + seg * 16);
  short8 v1 = *(const short8*)(t + row * 72 + seg * 16 + 8);
  short* dst = out + (size_t)bh * D_HEAD * S_LEN + (size_t)row * S_LEN + kb + seg * 16;
  *(short8*)dst = v0;
  *(short8*)(dst + 8) = v1;
}

template <bool BYTEMASK, bool PRE>
__device__ __forceinline__ void attn_body(
    char* smem, const float* Qg, const float* Kg, const float* Vg,
    const void* maskg, const short* Kbf, const short* Vtb,
    float* ctxg, float* attng) {

  const int tid = threadIdx.x;
  const int w = tid >> 6, l = tid & 63;
  const int lg = l >> 4, li = l & 15;
  const int rh = w >> 1, ch = w & 1;   // wave -> (row-half, col-half)
  const int qb = blockIdx.x, bh = blockIdx.y;
  const int qbase = qb * QBLK;

  const float* Qp = Qg + ((size_t)bh * S_LEN + qbase) * D_HEAD;
  const float* Kp = Kg + (size_t)bh * S_LEN * D_HEAD;
  const float* Vp = Vg + (size_t)bh * S_LEN * D_HEAD;
  const short* Kbp = Kbf + (size_t)bh * S_LEN * D_HEAD;
  const short* Vtp = Vtb + (size_t)bh * D_HEAD * S_LEN;
  float* attnp = attng + ((size_t)bh * S_LEN + qbase) * S_LEN;
  float* ctxp  = ctxg  + ((size_t)bh * S_LEN + qbase) * D_HEAD;
  const size_t mrow0 = ((size_t)bh * S_LEN + qbase) * S_LEN;

  // ---- staging helpers ----
  auto stageK = [&](int it, int buf) {
    char* kb = smem + KB_OFF + buf * 8192;
    if constexpr (PRE) {
      const int r0 = w * 16 + (l >> 3), ci = l & 7;
#pragma unroll
      for (int j = 0; j < 2; ++j) {
        int r = r0 + j * 8;
        const short* src = Kbp + ((size_t)(it * KBLK + r)) * D_HEAD + ((ci ^ (r & 7)) * 8);
        int off = __builtin_amdgcn_readfirstlane((w * 16 + j * 8) * 128);
        gload_lds16(src, kb + off);
      }
    } else {
      int key = tid >> 2, seg = tid & 3;
      const float* src = Kp + ((size_t)(it * KBLK + key)) * D_HEAD + seg * 16;
      float4 f0 = ((const float4*)src)[0];
      float4 f1 = ((const float4*)src)[1];
      float4 f2 = ((const float4*)src)[2];
      float4 f3 = ((const float4*)src)[3];
      short8 v0, v1;
      v0[0] = f2b(f0.x); v0[1] = f2b(f0.y); v0[2] = f2b(f0.z); v0[3] = f2b(f0.w);
      v0[4] = f2b(f1.x); v0[5] = f2b(f1.y); v0[6] = f2b(f1.z); v0[7] = f2b(f1.w);
      v1[0] = f2b(f2.x); v1[1] = f2b(f2.y); v1[2] = f2b(f2.z); v1[3] = f2b(f2.w);
      v1[4] = f2b(f3.x); v1[5] = f2b(f3.y); v1[6] = f2b(f3.z); v1[7] = f2b(f3.w);
      *(short8*)(kb + swz1(key, seg * 32)) = v0;
      *(short8*)(kb + swz1(key, seg * 32 + 16)) = v1;
    }
  };

  auto stageVt = [&](int it) {
    char* vb = smem + VT_OFF;
    if constexpr (PRE) {
      const int d0 = w * 16 + (l >> 3), ci = l & 7;
#pragma unroll
      for (int j = 0; j < 2; ++j) {
        int d = d0 + j * 8;
        const short* src = Vtp + (size_t)d * S_LEN + it * KBLK + ((ci ^ (d & 7)) * 8);
        int off = __builtin_amdgcn_readfirstlane((w * 16 + j * 8) * 128);
        gload_lds16(src, vb + off);
      }
    } else {
      int key = l, db = w;
      const float* src = Vp + ((size_t)(it * KBLK + key)) * D_HEAD + db * 16;
#pragma unroll
      for (int j = 0; j < 4; ++j) {
        float4 f = ((const float4*)src)[j];
        int dd = db * 16 + j * 4;
        *(short*)(vb + swz1(dd + 0, key * 2)) = f2b(f.x);
        *(short*)(vb + swz1(dd + 1, key * 2)) = f2b(f.y);
        *(short*)(vb + swz1(dd + 2, key * 2)) = f2b(f.z);
        *(short*)(vb + swz1(dd + 3, key * 2)) = f2b(f.w);
      }
    }
  };

  auto loadMask = [&](int it, unsigned* m) {
#pragma unroll
    for (int reg = 0; reg < 4; ++reg) {
      int row = rh * 16 + lg * 4 + reg;
#pragma unroll
      for (int ct = 0; ct < 2; ++ct) {
        size_t idx = mrow0 + (size_t)row * S_LEN + it * KBLK + ch * 32 + ct * 16 + li;
        if constexpr (BYTEMASK)
          m[ct * 4 + reg] = (unsigned)((const unsigned char*)maskg)[idx];
        else
          m[ct * 4 + reg] = ((const unsigned*)maskg)[idx];
      }
    }
  };

  auto qkt = [&](f32x4* accs, const short8* qf, int buf) {
    char* kb = smem + KB_OFF + buf * 8192;
#pragma unroll
    for (int ct = 0; ct < 2; ++ct) {
      int key = ch * 32 + ct * 16 + li;
      short8 b0 = *(const short8*)(kb + swz1(key, lg * 16));
      short8 b1 = *(const short8*)(kb + swz1(key, 64 + lg * 16));
      accs[ct] = __builtin_amdgcn_mfma_f32_16x16x32_bf16(qf[0], b0, accs[ct], 0, 0, 0);
      accs[ct] = __builtin_amdgcn_mfma_f32_16x16x32_bf16(qf[1], b1, accs[ct], 0, 0, 0);
    }
  };

  // ---- prologue: issue first K stage + first mask loads, stage Q ----
  stageK(0, 0);
  unsigned mc[8];
  loadMask(0, mc);
  {
    int row = tid >> 3, seg = tid & 7;
    const float* src = Qp + row * D_HEAD + seg * 8;
    float4 a = ((const float4*)src)[0];
    float4 b = ((const float4*)src)[1];
    short8 v;
    v[0] = f2b(a.x); v[1] = f2b(a.y); v[2] = f2b(a.z); v[3] = f2b(a.w);
    v[4] = f2b(b.x); v[5] = f2b(b.y); v[6] = f2b(b.z); v[7] = f2b(b.w);
    *(short8*)(smem + P_OFF + swz1(row, seg * 16)) = v;
  }
  __syncthreads();
  short8 qfrag[2];
  {
    int row = rh * 16 + li;
    qfrag[0] = *(const short8*)(smem + P_OFF + swz1(row, lg * 16));
    qfrag[1] = *(const short8*)(smem + P_OFF + swz1(row, 64 + lg * 16));
  }
  __syncthreads();

  // ================= pass 1: row sums of exp(s), mask bits -> LDS bytes ======
  float l_acc[4] = {0.f, 0.f, 0.f, 0.f};
  for (int it = 0; it < NITER; ++it) {
    const int cb = it & 1, nb = cb ^ 1;
    if (it + 1 < NITER) stageK(it + 1, nb);
    unsigned mn[8];
    if (it + 1 < NITER) loadMask(it + 1, mn);
    f32x4 accs[2] = {{0.f,0.f,0.f,0.f},{0.f,0.f,0.f,0.f}};
    qkt(accs, qfrag, cb);
    unsigned mbyte = 0;
#pragma unroll
    for (int reg = 0; reg < 4; ++reg) {
      float contrib = 0.f;
#pragma unroll
      for (int ct = 0; ct < 2; ++ct) {
        bool pred = mc[ct * 4 + reg] != 0u;
        mbyte |= (unsigned)pred << (ct * 4 + reg);
        float p = pred ? 0.f : __expf(accs[ct][reg] * 0.125f);
        contrib += p;
      }
      contrib += __shfl_xor(contrib, 1);
      contrib += __shfl_xor(contrib, 2);
      contrib += __shfl_xor(contrib, 4);
      contrib += __shfl_xor(contrib, 8);
      l_acc[reg] += contrib;
    }
    *(unsigned char*)(smem + MB_OFF + it * 256 + tid) = (unsigned char)mbyte;
    __syncthreads();
    if (it + 1 < NITER) {
#pragma unroll
      for (int i = 0; i < 8; ++i) mc[i] = mn[i];
    }
  }

  // combine col-half partial sums -> 1/l per row; prefetch pass-2 tiles
  if (li == 0) {
#pragma unroll
    for (int reg = 0; reg < 4; ++reg)
      *(float*)(smem + LP_OFF + ch * 128 + (rh * 16 + lg * 4 + reg) * 4) = l_acc[reg];
  }
  stageK(0, 0);     // buf0 free since it=30's barrier
  stageVt(0);
  __syncthreads();
  float linv[4];
#pragma unroll
  for (int reg = 0; reg < 4; ++reg) {
    int row = rh * 16 + lg * 4 + reg;
    float tot = *(const float*)(smem + LP_OFF + row * 4) +
                *(const float*)(smem + LP_OFF + 128 + row * 4);
    linv[reg] = 1.0f / tot;
  }

  // ================= pass 2: recompute, write attn, accumulate PV ============
  f32x4 acco[2] = {{0.f,0.f,0.f,0.f},{0.f,0.f,0.f,0.f}};
  for (int it = 0; it < NITER; ++it) {
    const int cb = it & 1, nb = cb ^ 1;
    if (it > 0) stageVt(it);                 // prior PV done (sync2 of it-1)
    if (it + 1 < NITER) stageK(it + 1, nb);
    f32x4 accs[2] = {{0.f,0.f,0.f,0.f},{0.f,0.f,0.f,0.f}};
    qkt(accs, qfrag, cb);
    unsigned mbyte = *(const unsigned char*)(smem + MB_OFF + it * 256 + tid);
#pragma unroll
    for (int reg = 0; reg < 4; ++reg) {
      int row = rh * 16 + lg * 4 + reg;
#pragma unroll
      for (int ct = 0; ct < 2; ++ct) {
        int col = ch * 32 + ct * 16 + li;
        bool pred = (mbyte >> (ct * 4 + reg)) & 1u;
        float p = pred ? 0.f : __expf(accs[ct][reg] * 0.125f) * linv[reg];
        *(short*)(smem + P_OFF + swz2(row, col * 2)) = f2b(p);
      }
    }
    __syncthreads();   // sync1: P complete; K(it+1)/Vt(it) drained
    // attn store from LDS (256B contiguous per 8 lanes)
    {
      int row = tid >> 3, seg = tid & 7;
      short8 pv = *(const short8*)(smem + P_OFF + swz2(row, seg * 16));
      float* dst = attnp + (size_t)row * S_LEN + it * KBLK + seg * 8;
      float4 f0, f1;
      f0.x = b2f(pv[0]); f0.y = b2f(pv[1]); f0.z = b2f(pv[2]); f0.w = b2f(pv[3]);
      f1.x = b2f(pv[4]); f1.y = b2f(pv[5]); f1.z = b2f(pv[6]); f1.w = b2f(pv[7]);
      ((float4*)dst)[0] = f0;
      ((float4*)dst)[1] = f1;
    }
    // PV: O(16x32 per wave) += P(16x64) * V(64xD tile)
#pragma unroll
    for (int ks = 0; ks < 2; ++ks) {
      int prow = rh * 16 + li;
      short8 af = *(const short8*)(smem + P_OFF + swz2(prow, ks * 64 + lg * 16));
#pragma unroll
      for (int ct2 = 0; ct2 < 2; ++ct2) {
        int d = ch * 32 + ct2 * 16 + li;
        short8 bf = *(const short8*)(smem + VT_OFF + swz1(d, ks * 64 + lg * 16));
        acco[ct2] = __builtin_amdgcn_mfma_f32_16x16x32_bf16(af, bf, acco[ct2], 0, 0, 0);
      }
    }
    __syncthreads();   // sync2
  }

  // epilogue: write context
#pragma unroll
  for (int ct2 = 0; ct2 < 2; ++ct2) {
#pragma unroll
    for (int reg = 0; reg < 4; ++reg) {
      int row = rh * 16 + lg * 4 + reg;
      int d = ch * 32 + ct2 * 16 + li;
      ctxp[(size_t)row * D_HEAD + d] = acco[ct2][reg];
    }
  }
}

template <bool PRE>
__global__ void __launch_bounds__(256, 4)
attn_kernel(const float* Q, const float* K, const float* V, const void* M,
            const short* Kbf, const short* Vtb,
            float* ctx, float* attn, const int* flag) {
  extern __shared__ char smem[];
  if (*flag)
    attn_body<true, PRE>(smem, Q, K, V, M, Kbf, Vtb, ctx, attn);
  else
    attn_body<false, PRE>(smem, Q, K, V, M, Kbf, Vtb, ctx, attn);
}

extern "C" void kernel_launch(void* const* d_in, const int* in_sizes, int n_in,
                              void* d_out, int out_size, void* d_ws, size_t ws_size,
                              hipStream_t stream) {
  const float* Q = (const float*)d_in[0];
  const float* K = (const float*)d_in[1];
  const float* V = (const float*)d_in[2];
  const void*  M = d_in[3];
  float* ctx  = (float*)d_out;
  float* attn = ctx + (size_t)NBH * S_LEN * D_HEAD;   // context first, then attn
  int* flag = (int*)d_ws;
  short* Kbf = (short*)((char*)d_ws + 256);
  short* Vtb = Kbf + (size_t)NBH * S_LEN * D_HEAD;
  const size_t PRE_BYTES = 256 + (size_t)2 * NBH * S_LEN * D_HEAD * sizeof(short);

  hipMemsetAsync(flag, 0, sizeof(int), stream);
  detect_mask_kernel<<<dim3(16), dim3(256), 0, stream>>>((const unsigned*)M, flag);

  dim3 grid(S_LEN / QBLK, NBH);
  if (ws_size >= PRE_BYTES) {
    convK_kernel<<<dim3(4096), dim3(256), 0, stream>>>(K, Kbf);
    convVT_kernel<<<dim3(32, 64), dim3(256), 0, stream>>>(V, Vtb);
    attn_kernel<true><<<grid, dim3(256), SMEM_BYTES, stream>>>(
        Q, K, V, M, Kbf, Vtb, ctx, attn, flag);
  } else {
    attn_kernel<false><<<grid, dim3(256), SMEM_BYTES, stream>>>(
        Q, K, V, M, Kbf, Vtb, ctx, attn, flag);
  }
}